// Round 15
// baseline (215.981 us; speedup 1.0000x reference)
//
#include <hip/hip_runtime.h>

#define NGS 25
#define NGX 40
#define NGY 40
#define KK  64
#define NB2 4
#define NYY 1000
#define DAMP 0.01f

typedef __attribute__((ext_vector_type(8))) short short8;
typedef __attribute__((ext_vector_type(4))) float f32x4;

__device__ __forceinline__ short bf16_rn(float x) {
  unsigned u = __float_as_uint(x);
  u = u + 0x7fffu + ((u >> 16) & 1u);
  return (short)(u >> 16);
}
__device__ __forceinline__ float bf16_tof(short s) {
  return __uint_as_float(((unsigned)(unsigned short)s) << 16);
}

// ---------------- Kernel 1: 3-deep pipelined direct-fragment MFMA Gram -------
// Round-12 proven loop body; ONLY change = 3-deep register pipeline (loads of
// I+1 and I+2 in flight during CONSUME(I) -> full ~900cy HBM latency hidden)
// + amdgpu_waves_per_eu(2,2) so the allocator targets 2 waves/EU (256-reg
// budget) instead of squeezing to 128 and spilling (round-13 failure mode).
__global__ __attribute__((amdgpu_waves_per_eu(2, 2))) __launch_bounds__(256)
void k_gram(
    const float* __restrict__ xin, const float* __restrict__ hist,
    float* __restrict__ Gws)
{
  __shared__ float Gs[KK][KK + 5];

  const int tile = blockIdx.x;
  const int gx = tile / NGY, gy = tile % NGY;
  const size_t base = (size_t)(gx * NGS) * NYY + (size_t)(gy * NGS);
  const int tid  = threadIdx.x;
  const int wave = tid >> 6;
  const int lane = tid & 63;
  const int u    = lane >> 4;
  const int col  = lane & 15;
  const bool tail = (u == 3);
  const int off  = tail ? 17 : (8 * u);   // tail window shifted in-bounds

  f32x4 accG[10];
  f32x4 accA[4];
  #pragma unroll
  for (int j = 0; j < 10; ++j) { accG[j].x = 0.f; accG[j].y = 0.f; accG[j].z = 0.f; accG[j].w = 0.f; }
  #pragma unroll
  for (int j = 0; j < 4; ++j) { accA[j].x = 0.f; accA[j].y = 0.f; accA[j].z = 0.f; accA[j].w = 0.f; }

  const int xch = (col < 4) ? col : 3;

  const float* pbase[5];
  #pragma unroll
  for (int s = 0; s < 4; ++s) pbase[s] = hist + (size_t)(16 * s + col) * 1000000 + base + off;
  pbase[4] = xin + (size_t)xch * 1000000 + base + off;

  float bufA[40], bufB[40], bufC[40];

#define LOADIT(BUF, I) { \
    const int r_ = wave + 4 * (I); \
    const size_t ro_ = (size_t)((r_ < NGS) ? r_ : 0) * NYY; \
    _Pragma("unroll") \
    for (int s_ = 0; s_ < 5; ++s_) { \
      _Pragma("unroll") \
      for (int e_ = 0; e_ < 8; ++e_) BUF[s_ * 8 + e_] = pbase[s_][ro_ + e_]; \
    } }

#define CONSUME(BUF, I) { \
    const int r_ = wave + 4 * (I); \
    const bool ok_ = (r_ < NGS); \
    short8 fh[5], fl[5]; \
    _Pragma("unroll") \
    for (int s_ = 0; s_ < 5; ++s_) { \
      _Pragma("unroll") \
      for (int e_ = 0; e_ < 8; ++e_) { \
        float x_ = BUF[s_ * 8 + e_]; \
        if (tail) x_ = (e_ == 0) ? BUF[s_ * 8 + 7] : 0.f; \
        if (!ok_) x_ = 0.f; \
        if (s_ == 4 && col >= 4) x_ = 0.f; \
        const short h_ = (short)(__float_as_uint(x_) >> 16); \
        fh[s_][e_] = h_; \
        fl[s_][e_] = bf16_rn(x_ - bf16_tof(h_)); \
      } \
    } \
    _Pragma("unroll") \
    for (int si_ = 0; si_ < 4; ++si_) \
      _Pragma("unroll") \
      for (int sj_ = 0; sj_ < 4; ++sj_) { \
        if (sj_ >= si_) { \
          const int ix_ = si_ * 4 - (si_ * (si_ + 1)) / 2 + sj_; \
          accG[ix_] = __builtin_amdgcn_mfma_f32_16x16x32_bf16(fh[si_], fh[sj_], accG[ix_], 0, 0, 0); \
          accG[ix_] = __builtin_amdgcn_mfma_f32_16x16x32_bf16(fh[si_], fl[sj_], accG[ix_], 0, 0, 0); \
          accG[ix_] = __builtin_amdgcn_mfma_f32_16x16x32_bf16(fl[si_], fh[sj_], accG[ix_], 0, 0, 0); \
        } \
      } \
    _Pragma("unroll") \
    for (int s_ = 0; s_ < 4; ++s_) { \
      accA[s_] = __builtin_amdgcn_mfma_f32_16x16x32_bf16(fh[4], fh[s_], accA[s_], 0, 0, 0); \
      accA[s_] = __builtin_amdgcn_mfma_f32_16x16x32_bf16(fh[4], fl[s_], accA[s_], 0, 0, 0); \
      accA[s_] = __builtin_amdgcn_mfma_f32_16x16x32_bf16(fl[4], fh[s_], accA[s_], 0, 0, 0); \
    } }

  LOADIT(bufA, 0)
  LOADIT(bufB, 1)
  LOADIT(bufC, 2)
  CONSUME(bufA, 0) LOADIT(bufA, 3)
  CONSUME(bufB, 1) LOADIT(bufB, 4)
  CONSUME(bufC, 2) LOADIT(bufC, 5)
  CONSUME(bufA, 3) LOADIT(bufA, 6)
  CONSUME(bufB, 4)
  CONSUME(bufC, 5)
  CONSUME(bufA, 6)

#undef LOADIT
#undef CONSUME

  // ---- cross-wave reduction into Gs (+damping, symmetric mirror) -----------
  __syncthreads();
  for (int g = 0; g < 4; ++g) {
    if (wave == g) {
      #pragma unroll
      for (int si = 0; si < 4; ++si)
        #pragma unroll
        for (int sj = 0; sj < 4; ++sj) {
          if (sj >= si) {
            const int ix = si * 4 - (si * (si + 1)) / 2 + sj;
            #pragma unroll
            for (int q = 0; q < 4; ++q) {
              const float val = (q == 0) ? accG[ix].x : (q == 1) ? accG[ix].y
                              : (q == 2) ? accG[ix].z : accG[ix].w;
              const int r0 = 16 * si + 4 * u + q;
              const int c0 = 16 * sj + col;
              if (g == 0) {
                Gs[r0][c0] = val + ((r0 == c0) ? DAMP : 0.f);
                if (si != sj) Gs[c0][r0] = val;
              } else {
                Gs[r0][c0] += val;
                if (si != sj) Gs[c0][r0] += val;
              }
            }
          }
        }
      if (lane < 16) {
        #pragma unroll
        for (int s = 0; s < 4; ++s) {
          #pragma unroll
          for (int q = 0; q < 4; ++q) {
            const float val = (q == 0) ? accA[s].x : (q == 1) ? accA[s].y
                            : (q == 2) ? accA[s].z : accA[s].w;
            if (g == 0) Gs[16 * s + lane][KK + q] = val;
            else        Gs[16 * s + lane][KK + q] += val;
          }
        }
      }
    }
    __syncthreads();
  }

  // ---- write 64x68 panel (G | A^T) to workspace, coalesced ------------------
  float* dst = Gws + (size_t)tile * (KK * 68);
  for (int idx = tid; idx < KK * 68; idx += 256) {
    const int r = idx / 68, c = idx - r * 68;
    dst[idx] = Gs[r][c];
  }
}

// ---------------- Kernel 1b: per-tile register Gauss-Jordan solve -> AG ------
__global__ __launch_bounds__(256) void k_solve(
    const float* __restrict__ Gws, float* __restrict__ AG)
{
  __shared__ float prow[144];
  const int tile = blockIdx.x;
  const int tid  = threadIdx.x;
  const int lane = tid & 63;
  const int ei = tid >> 2, eq = tid & 3;
  const float* Gt = Gws + (size_t)tile * (KK * 68);

  float w[17];
  #pragma unroll
  for (int jj = 0; jj < 17; ++jj) w[jj] = Gt[ei * 68 + 4 * jj + eq];

  float myDiag = 1.f;
  if (ei == 0) {
    #pragma unroll
    for (int jj = 0; jj < 17; ++jj) prow[4 * jj + eq] = w[jj];
  }
  __syncthreads();

  #pragma unroll
  for (int k = 0; k < KK; ++k) {
    const float* pr = prow + (k & 1) * 72;
    const float piv = pr[k];
    const float num = __shfl(w[k >> 2], (lane & ~3) | (k & 3), 64);
    const float f = (ei == k) ? 0.f : (num / piv);
    if (ei == k) myDiag = piv;
    #pragma unroll
    for (int jj = (k < 3 ? 0 : (k - 2) >> 2); jj < 17; ++jj)
      w[jj] -= f * pr[4 * jj + eq];
    if (k < KK - 1) {
      if (ei == k + 1) {
        float* pw = prow + ((k + 1) & 1) * 72;
        #pragma unroll
        for (int jj = 0; jj < 17; ++jj) pw[4 * jj + eq] = w[jj];
      }
    }
    __syncthreads();
  }

  AG[(size_t)tile * 256 + eq * 64 + ei] = w[16] / myDiag;
}

// ---------------- Kernel 2: coalesced row-strip Y = AG * V -------------------
__global__ __launch_bounds__(256) void k_project(
    const float* __restrict__ hist, const float* __restrict__ AG,
    float* __restrict__ out)
{
  __shared__ float ag[NGY * 260];
  const int i  = blockIdx.x;          // image row 0..999
  const int gx = i / NGS;
  const int tid = threadIdx.x;

  for (int idx = tid; idx < NGY * 256; idx += 256) {
    const int t = idx >> 8, rem = idx & 255;
    const int c = rem >> 6, k = rem & 63;
    ag[t * 260 + k * 4 + c] = AG[(size_t)(gx * NGY + t) * 256 + rem];
  }
  __syncthreads();

  const int py0 = 4 * tid;
  if (py0 < NYY) {
    const int g0 = (py0    ) / NGS, g1 = (py0 + 1) / NGS;
    const int g2 = (py0 + 2) / NGS, g3 = (py0 + 3) / NGS;
    f32x4 o0 = {0,0,0,0}, o1 = {0,0,0,0}, o2 = {0,0,0,0}, o3 = {0,0,0,0};
    const float* hp = hist + (size_t)i * NYY + py0;
    #pragma unroll 8
    for (int k = 0; k < KK; ++k) {
      const float4 v = *(const float4*)(hp + (size_t)k * 1000000);
      const f32x4 a0 = *(const f32x4*)&ag[g0 * 260 + k * 4];
      const f32x4 a1 = *(const f32x4*)&ag[g1 * 260 + k * 4];
      const f32x4 a2 = *(const f32x4*)&ag[g2 * 260 + k * 4];
      const f32x4 a3 = *(const f32x4*)&ag[g3 * 260 + k * 4];
      o0 += a0 * v.x; o1 += a1 * v.y; o2 += a2 * v.z; o3 += a3 * v.w;
    }
    #pragma unroll
    for (int c = 0; c < 4; ++c) {
      float4 w4;
      w4.x = o0[c]; w4.y = o1[c]; w4.z = o2[c]; w4.w = o3[c];
      *(float4*)(out + (size_t)c * 1000000 + (size_t)i * NYY + py0) = w4;
    }
  }
}

extern "C" void kernel_launch(void* const* d_in, const int* in_sizes, int n_in,
                              void* d_out, int out_size, void* d_ws, size_t ws_size,
                              hipStream_t stream) {
  const float* xin  = (const float*)d_in[0];   // local_x  (1,4,1000,1000)
  const float* hist = (const float*)d_in[1];   // ms_history (1,16,4,1000,1000)
  float* out = (float*)d_out;
  float* AG  = (float*)d_ws;                       // 1600*256 floats = 1.6 MB
  float* Gws = (float*)d_ws + 1600 * 256;          // 1600 * 64*68 floats = 27.9 MB

  k_gram   <<<NGX * NGY, 256, 0, stream>>>(xin, hist, Gws);
  k_solve  <<<NGX * NGY, 256, 0, stream>>>(Gws, AG);
  k_project<<<NYY, 256, 0, stream>>>(hist, AG, out);
}

// Round 16
// 193.394 us; speedup vs baseline: 1.1168x; 1.1168x over previous
//
#include <hip/hip_runtime.h>

#define NGS 25
#define NGX 40
#define NGY 40
#define KK  64
#define NB2 4
#define NYY 1000
#define DAMP 0.01f

typedef __attribute__((ext_vector_type(8))) short short8;
typedef __attribute__((ext_vector_type(4))) float f32x4;
typedef f32x4 uf4 __attribute__((aligned(4)));   // 4B-aligned float4 loads

__device__ __forceinline__ short bf16_rn(float x) {
  unsigned u = __float_as_uint(x);
  u = u + 0x7fffu + ((u >> 16) & 1u);
  return (short)(u >> 16);
}
__device__ __forceinline__ float bf16_tof(short s) {
  return __uint_as_float(((unsigned)(unsigned short)s) << 16);
}

// ---------------- Kernel 1: 3-deep pipelined direct-fragment MFMA Gram -------
// r15 post-mortem: VGPR=88 proved the scheduler sank the prefetch loads next
// to their uses (no MLP). Fixes: (1) sched_barrier(0) fences pin the
// LOAD/CONSUME segment order; (2) float4 loads -> 10 VMEM ops per buffer
// (3-deep = 30 outstanding < 63 vmcnt queue) instead of 40 scalars (80 > 63).
__global__ __attribute__((amdgpu_waves_per_eu(2, 2))) __launch_bounds__(256)
void k_gram(
    const float* __restrict__ xin, const float* __restrict__ hist,
    float* __restrict__ Gws)
{
  __shared__ float Gs[KK][KK + 5];

  const int tile = blockIdx.x;
  const int gx = tile / NGY, gy = tile % NGY;
  const size_t base = (size_t)(gx * NGS) * NYY + (size_t)(gy * NGS);
  const int tid  = threadIdx.x;
  const int wave = tid >> 6;
  const int lane = tid & 63;
  const int u    = lane >> 4;
  const int col  = lane & 15;
  const bool tail = (u == 3);
  const int off  = tail ? 17 : (8 * u);   // tail window py17..24 (in-bounds)

  f32x4 accG[10];
  f32x4 accA[4];
  #pragma unroll
  for (int j = 0; j < 10; ++j) { accG[j].x = 0.f; accG[j].y = 0.f; accG[j].z = 0.f; accG[j].w = 0.f; }
  #pragma unroll
  for (int j = 0; j < 4; ++j) { accA[j].x = 0.f; accA[j].y = 0.f; accA[j].z = 0.f; accA[j].w = 0.f; }

  const int xch = (col < 4) ? col : 3;

  const float* pbase[5];
  #pragma unroll
  for (int s = 0; s < 4; ++s) pbase[s] = hist + (size_t)(16 * s + col) * 1000000 + base + off;
  pbase[4] = xin + (size_t)xch * 1000000 + base + off;

  f32x4 bufA[10], bufB[10], bufC[10];

#define LOADIT(BUF, I) { \
    const int r_ = wave + 4 * (I); \
    const size_t ro_ = (size_t)((r_ < NGS) ? r_ : 0) * NYY; \
    _Pragma("unroll") \
    for (int s_ = 0; s_ < 5; ++s_) { \
      BUF[s_ * 2 + 0] = *(const uf4*)(pbase[s_] + ro_); \
      BUF[s_ * 2 + 1] = *(const uf4*)(pbase[s_] + ro_ + 4); \
    } \
    __builtin_amdgcn_sched_barrier(0); }

#define CONSUME(BUF, I) { \
    const int r_ = wave + 4 * (I); \
    const bool ok_ = (r_ < NGS); \
    short8 fh[5], fl[5]; \
    _Pragma("unroll") \
    for (int s_ = 0; s_ < 5; ++s_) { \
      _Pragma("unroll") \
      for (int e_ = 0; e_ < 8; ++e_) { \
        float x_ = BUF[s_ * 2 + (e_ >> 2)][e_ & 3]; \
        if (tail) x_ = (e_ == 0) ? BUF[s_ * 2 + 1][3] : 0.f; \
        if (!ok_) x_ = 0.f; \
        if (s_ == 4 && col >= 4) x_ = 0.f; \
        const short h_ = (short)(__float_as_uint(x_) >> 16); \
        fh[s_][e_] = h_; \
        fl[s_][e_] = bf16_rn(x_ - bf16_tof(h_)); \
      } \
    } \
    _Pragma("unroll") \
    for (int si_ = 0; si_ < 4; ++si_) \
      _Pragma("unroll") \
      for (int sj_ = 0; sj_ < 4; ++sj_) { \
        if (sj_ >= si_) { \
          const int ix_ = si_ * 4 - (si_ * (si_ + 1)) / 2 + sj_; \
          accG[ix_] = __builtin_amdgcn_mfma_f32_16x16x32_bf16(fh[si_], fh[sj_], accG[ix_], 0, 0, 0); \
          accG[ix_] = __builtin_amdgcn_mfma_f32_16x16x32_bf16(fh[si_], fl[sj_], accG[ix_], 0, 0, 0); \
          accG[ix_] = __builtin_amdgcn_mfma_f32_16x16x32_bf16(fl[si_], fh[sj_], accG[ix_], 0, 0, 0); \
        } \
      } \
    _Pragma("unroll") \
    for (int s_ = 0; s_ < 4; ++s_) { \
      accA[s_] = __builtin_amdgcn_mfma_f32_16x16x32_bf16(fh[4], fh[s_], accA[s_], 0, 0, 0); \
      accA[s_] = __builtin_amdgcn_mfma_f32_16x16x32_bf16(fh[4], fl[s_], accA[s_], 0, 0, 0); \
      accA[s_] = __builtin_amdgcn_mfma_f32_16x16x32_bf16(fl[4], fh[s_], accA[s_], 0, 0, 0); \
    } \
    __builtin_amdgcn_sched_barrier(0); }

  LOADIT(bufA, 0)
  LOADIT(bufB, 1)
  LOADIT(bufC, 2)
  CONSUME(bufA, 0) LOADIT(bufA, 3)
  CONSUME(bufB, 1) LOADIT(bufB, 4)
  CONSUME(bufC, 2) LOADIT(bufC, 5)
  CONSUME(bufA, 3) LOADIT(bufA, 6)
  CONSUME(bufB, 4)
  CONSUME(bufC, 5)
  CONSUME(bufA, 6)

#undef LOADIT
#undef CONSUME

  // ---- cross-wave reduction into Gs (+damping, symmetric mirror) -----------
  __syncthreads();
  for (int g = 0; g < 4; ++g) {
    if (wave == g) {
      #pragma unroll
      for (int si = 0; si < 4; ++si)
        #pragma unroll
        for (int sj = 0; sj < 4; ++sj) {
          if (sj >= si) {
            const int ix = si * 4 - (si * (si + 1)) / 2 + sj;
            #pragma unroll
            for (int q = 0; q < 4; ++q) {
              const float val = (q == 0) ? accG[ix].x : (q == 1) ? accG[ix].y
                              : (q == 2) ? accG[ix].z : accG[ix].w;
              const int r0 = 16 * si + 4 * u + q;
              const int c0 = 16 * sj + col;
              if (g == 0) {
                Gs[r0][c0] = val + ((r0 == c0) ? DAMP : 0.f);
                if (si != sj) Gs[c0][r0] = val;
              } else {
                Gs[r0][c0] += val;
                if (si != sj) Gs[c0][r0] += val;
              }
            }
          }
        }
      if (lane < 16) {
        #pragma unroll
        for (int s = 0; s < 4; ++s) {
          #pragma unroll
          for (int q = 0; q < 4; ++q) {
            const float val = (q == 0) ? accA[s].x : (q == 1) ? accA[s].y
                            : (q == 2) ? accA[s].z : accA[s].w;
            if (g == 0) Gs[16 * s + lane][KK + q] = val;
            else        Gs[16 * s + lane][KK + q] += val;
          }
        }
      }
    }
    __syncthreads();
  }

  // ---- write 64x68 panel (G | A^T) to workspace, coalesced ------------------
  float* dst = Gws + (size_t)tile * (KK * 68);
  for (int idx = tid; idx < KK * 68; idx += 256) {
    const int r = idx / 68, c = idx - r * 68;
    dst[idx] = Gs[r][c];
  }
}

// ---------------- Kernel 1b: per-tile register Gauss-Jordan solve -> AG ------
__global__ __launch_bounds__(256) void k_solve(
    const float* __restrict__ Gws, float* __restrict__ AG)
{
  __shared__ float prow[144];
  const int tile = blockIdx.x;
  const int tid  = threadIdx.x;
  const int lane = tid & 63;
  const int ei = tid >> 2, eq = tid & 3;
  const float* Gt = Gws + (size_t)tile * (KK * 68);

  float w[17];
  #pragma unroll
  for (int jj = 0; jj < 17; ++jj) w[jj] = Gt[ei * 68 + 4 * jj + eq];

  float myDiag = 1.f;
  if (ei == 0) {
    #pragma unroll
    for (int jj = 0; jj < 17; ++jj) prow[4 * jj + eq] = w[jj];
  }
  __syncthreads();

  #pragma unroll
  for (int k = 0; k < KK; ++k) {
    const float* pr = prow + (k & 1) * 72;
    const float piv = pr[k];
    const float num = __shfl(w[k >> 2], (lane & ~3) | (k & 3), 64);
    const float f = (ei == k) ? 0.f : (num / piv);
    if (ei == k) myDiag = piv;
    #pragma unroll
    for (int jj = (k < 3 ? 0 : (k - 2) >> 2); jj < 17; ++jj)
      w[jj] -= f * pr[4 * jj + eq];
    if (k < KK - 1) {
      if (ei == k + 1) {
        float* pw = prow + ((k + 1) & 1) * 72;
        #pragma unroll
        for (int jj = 0; jj < 17; ++jj) pw[4 * jj + eq] = w[jj];
      }
    }
    __syncthreads();
  }

  AG[(size_t)tile * 256 + eq * 64 + ei] = w[16] / myDiag;
}

// ---------------- Kernel 2: coalesced row-strip Y = AG * V -------------------
__global__ __launch_bounds__(256) void k_project(
    const float* __restrict__ hist, const float* __restrict__ AG,
    float* __restrict__ out)
{
  __shared__ float ag[NGY * 260];
  const int i  = blockIdx.x;          // image row 0..999
  const int gx = i / NGS;
  const int tid = threadIdx.x;

  for (int idx = tid; idx < NGY * 256; idx += 256) {
    const int t = idx >> 8, rem = idx & 255;
    const int c = rem >> 6, k = rem & 63;
    ag[t * 260 + k * 4 + c] = AG[(size_t)(gx * NGY + t) * 256 + rem];
  }
  __syncthreads();

  const int py0 = 4 * tid;
  if (py0 < NYY) {
    const int g0 = (py0    ) / NGS, g1 = (py0 + 1) / NGS;
    const int g2 = (py0 + 2) / NGS, g3 = (py0 + 3) / NGS;
    f32x4 o0 = {0,0,0,0}, o1 = {0,0,0,0}, o2 = {0,0,0,0}, o3 = {0,0,0,0};
    const float* hp = hist + (size_t)i * NYY + py0;
    #pragma unroll 8
    for (int k = 0; k < KK; ++k) {
      const float4 v = *(const float4*)(hp + (size_t)k * 1000000);
      const f32x4 a0 = *(const f32x4*)&ag[g0 * 260 + k * 4];
      const f32x4 a1 = *(const f32x4*)&ag[g1 * 260 + k * 4];
      const f32x4 a2 = *(const f32x4*)&ag[g2 * 260 + k * 4];
      const f32x4 a3 = *(const f32x4*)&ag[g3 * 260 + k * 4];
      o0 += a0 * v.x; o1 += a1 * v.y; o2 += a2 * v.z; o3 += a3 * v.w;
    }
    #pragma unroll
    for (int c = 0; c < 4; ++c) {
      float4 w4;
      w4.x = o0[c]; w4.y = o1[c]; w4.z = o2[c]; w4.w = o3[c];
      *(float4*)(out + (size_t)c * 1000000 + (size_t)i * NYY + py0) = w4;
    }
  }
}

extern "C" void kernel_launch(void* const* d_in, const int* in_sizes, int n_in,
                              void* d_out, int out_size, void* d_ws, size_t ws_size,
                              hipStream_t stream) {
  const float* xin  = (const float*)d_in[0];   // local_x  (1,4,1000,1000)
  const float* hist = (const float*)d_in[1];   // ms_history (1,16,4,1000,1000)
  float* out = (float*)d_out;
  float* AG  = (float*)d_ws;                       // 1600*256 floats = 1.6 MB
  float* Gws = (float*)d_ws + 1600 * 256;          // 1600 * 64*68 floats = 27.9 MB

  k_gram   <<<NGX * NGY, 256, 0, stream>>>(xin, hist, Gws);
  k_solve  <<<NGX * NGY, 256, 0, stream>>>(Gws, AG);
  k_project<<<NYY, 256, 0, stream>>>(hist, AG, out);
}